// Round 22
// baseline (346.501 us; speedup 1.0000x reference)
//
#include <hip/hip_runtime.h>
#include <math.h>

#define BATCH 2
#define SEQ   2048
#define DIMIN 1024
#define NHEAD 8
#define DHEAD 64
#define INNER 512
#define KNEI  64
#define SCALE 0.125f
#define GBAND 2e-6f     // ambiguity band: ~2x cross-implementation score noise

typedef float v4f __attribute__((ext_vector_type(4)));   // native vec for NT ld/st

// ---------------------------------------------------------------------------
// K1 v9 (r21, ~140us): 64x64 tile, 4x4 micro, BK=16 + register-prefetch
// double buffering. Chain: single acc, kk ascending 0..1023, fmaf —
// bit-identical scores.
// ---------------------------------------------------------------------------
__global__ __launch_bounds__(256) void proj_kernel(
    const float* __restrict__ x, const float* __restrict__ Wq,
    const float* __restrict__ Wk, float* __restrict__ qk)
{
  const int which = blockIdx.z;                 // 0 = q, 1 = k
  const float* __restrict__ W = which ? Wk : Wq;
  float* __restrict__ out = qk + (size_t)which * (4096ull * (size_t)INNER);
  const int m0 = blockIdx.y * 64;
  const int n0 = blockIdx.x * 64;
  __shared__ float aT[16][68];   // x tile transposed [k][m]
  __shared__ float bS[16][68];   // W tile [k][n]
  const int t  = threadIdx.x;
  const int ty = t >> 4, tx = t & 15;
  const int am = t >> 2, ac4 = t & 3;           // A: row m, k-chunk ac4*4
  const int bk = t >> 6, bn = t & 63;           // B: k-row bk(+4s), col bn
  const float* __restrict__ xrow = x + (size_t)(m0 + am) * DIMIN;
  const float* __restrict__ wcol = W + bn + n0;

  float4 ar;        // prefetched A fragment
  float  br[4];     // prefetched B fragment
  ar = *(const float4*)(xrow + 0 + ac4 * 4);
  #pragma unroll
  for (int s5 = 0; s5 < 4; ++s5)
    br[s5] = wcol[(size_t)(0 + bk + 4*s5) * INNER];

  float acc[4][4] = {};
  for (int k0 = 0; k0 < DIMIN; k0 += 16) {
    __syncthreads();   // prior compute done -> safe to overwrite LDS
    aT[ac4*4+0][am] = ar.x; aT[ac4*4+1][am] = ar.y;
    aT[ac4*4+2][am] = ar.z; aT[ac4*4+3][am] = ar.w;
    #pragma unroll
    for (int s5 = 0; s5 < 4; ++s5)
      bS[bk + 4*s5][bn] = br[s5];
    __syncthreads();
    if (k0 + 16 < DIMIN) {   // issue next tile's loads; retire under FMAs
      ar = *(const float4*)(xrow + (k0 + 16) + ac4 * 4);
      #pragma unroll
      for (int s5 = 0; s5 < 4; ++s5)
        br[s5] = wcol[(size_t)(k0 + 16 + bk + 4*s5) * INNER];
    }
    #pragma unroll 4
    for (int kk = 0; kk < 16; ++kk) {   // strictly sequential in global k
      float4 a4 = *(const float4*)&aT[kk][ty*4];
      float4 b4 = *(const float4*)&bS[kk][tx*4];
      float a[4] = {a4.x, a4.y, a4.z, a4.w};
      float b[4] = {b4.x, b4.y, b4.z, b4.w};
      #pragma unroll
      for (int i = 0; i < 4; ++i)
        #pragma unroll
        for (int j = 0; j < 4; ++j)
          acc[i][j] = fmaf(a[i], b[j], acc[i][j]);
    }
  }
  #pragma unroll
  for (int i = 0; i < 4; ++i) {
    float4 v = make_float4(acc[i][0], acc[i][1], acc[i][2], acc[i][3]);
    *(float4*)(out + (size_t)(m0 + ty*4 + i) * INNER + n0 + tx*4) = v;
  }
}

// ---------------------------------------------------------------------------
// K2: scores = q @ k^T * SCALE per (b,h).  128x128 tile, 8x8 microtile,
// one-shot LDS stage (K=64).  kk ascending 0..63, single acc — bit-identical.
// ---------------------------------------------------------------------------
__global__ __launch_bounds__(256) void score_kernel(
    const float* __restrict__ qk, float* __restrict__ out)
{
  const int bh = blockIdx.z;            // b*8+h
  const int b  = bh >> 3, h = bh & 7;
  const int m0 = blockIdx.y * 128;      // q rows
  const int n0 = blockIdx.x * 128;      // keys
  const float* __restrict__ q = qk;
  const float* __restrict__ k = qk + 4096ull * (size_t)INNER;
  __shared__ float qT[64][136];         // [d][m]
  __shared__ float kT[64][136];         // [d][key]
  const int t = threadIdx.x;
  {
    #pragma unroll
    for (int p = 0; p < 2; ++p) {
      const int r  = p*64 + (t >> 2);       // tile row 0..127
      const int d0 = (t & 3) * 16;          // within-row d base
      const float* qrow = q + (size_t)(b*SEQ + m0 + r) * INNER + h*DHEAD + d0;
      const float* krow = k + (size_t)(b*SEQ + n0 + r) * INNER + h*DHEAD + d0;
      #pragma unroll
      for (int s = 0; s < 4; ++s) {
        float4 qv = *(const float4*)(qrow + s*4);
        float4 kv = *(const float4*)(krow + s*4);
        qT[d0+s*4+0][r] = qv.x; qT[d0+s*4+1][r] = qv.y;
        qT[d0+s*4+2][r] = qv.z; qT[d0+s*4+3][r] = qv.w;
        kT[d0+s*4+0][r] = kv.x; kT[d0+s*4+1][r] = kv.y;
        kT[d0+s*4+2][r] = kv.z; kT[d0+s*4+3][r] = kv.w;
      }
    }
  }
  __syncthreads();
  const int ty = t >> 4, tx = t & 15;
  float acc[8][8] = {};
  #pragma unroll 2
  for (int kk = 0; kk < 64; ++kk) {
    float4 a0 = *(const float4*)&qT[kk][ty*8];
    float4 a1 = *(const float4*)&qT[kk][ty*8+4];
    float4 b0 = *(const float4*)&kT[kk][tx*8];
    float4 b1 = *(const float4*)&kT[kk][tx*8+4];
    float a[8] = {a0.x,a0.y,a0.z,a0.w,a1.x,a1.y,a1.z,a1.w};
    float bb[8]= {b0.x,b0.y,b0.z,b0.w,b1.x,b1.y,b1.z,b1.w};
    #pragma unroll
    for (int i = 0; i < 8; ++i)
      #pragma unroll
      for (int j = 0; j < 8; ++j)
        acc[i][j] = fmaf(a[i], bb[j], acc[i][j]);
  }
  #pragma unroll
  for (int i = 0; i < 8; ++i) {
    float* orow = out + ((size_t)bh * SEQ + m0 + ty*8 + i) * SEQ + n0 + tx*8;
    *(float4*)(orow)     = make_float4(acc[i][0]*SCALE, acc[i][1]*SCALE,
                                       acc[i][2]*SCALE, acc[i][3]*SCALE);
    *(float4*)(orow + 4) = make_float4(acc[i][4]*SCALE, acc[i][5]*SCALE,
                                       acc[i][6]*SCALE, acc[i][7]*SCALE);
  }
}

// ---------------------------------------------------------------------------
// K3: per-row top-64 + hedged softmax, in place. 1 row/wave, reversed row
// order + NONTEMPORAL loads (scores are read-once streaming) + NT stores.
// ---------------------------------------------------------------------------
__device__ __forceinline__ unsigned f2key(float f) {
  unsigned u = __float_as_uint(f);
  return (u & 0x80000000u) ? ~u : (u | 0x80000000u);
}
__device__ __forceinline__ float key2f(unsigned kk) {
  unsigned u = (kk & 0x80000000u) ? (kk & 0x7FFFFFFFu) : ~kk;
  return __uint_as_float(u);
}

__global__ __launch_bounds__(256) void topk_softmax_hedge(float* __restrict__ out)
{
  const int wave = threadIdx.x >> 6;
  const int lane = threadIdx.x & 63;
  const size_t row = (size_t)(gridDim.x - 1 - blockIdx.x) * 4 + wave;  // reversed
  float* __restrict__ p = out + row * (size_t)SEQ;

  float s[32];
  #pragma unroll
  for (int i = 0; i < 8; ++i) {
    v4f v = __builtin_nontemporal_load((const v4f*)(p + (size_t)(lane + 64*i) * 4));
    s[i*4+0] = v.x; s[i*4+1] = v.y; s[i*4+2] = v.z; s[i*4+3] = v.w;
  }

  float mx = s[0], mn = s[0];
  #pragma unroll
  for (int i = 1; i < 32; ++i) { mx = fmaxf(mx, s[i]); mn = fminf(mn, s[i]); }
  #pragma unroll
  for (int o = 32; o; o >>= 1) {
    mx = fmaxf(mx, __shfl_xor(mx, o));
    mn = fminf(mn, __shfl_xor(mn, o));
  }

  // bisection with ballot counting; early exit at count==64.
  unsigned lo = f2key(mn);
  unsigned hi = f2key(mx) + 1u;
  while (lo + 1u < hi) {
    const unsigned mid = lo + ((hi - lo) >> 1);
    const float tf = key2f(mid);
    int c = 0;
    #pragma unroll
    for (int i = 0; i < 32; ++i)
      c += __popcll(__ballot(s[i] >= tf));          // wave-uniform
    if (c >= KNEI) { lo = mid; if (c == KNEI) break; }
    else hi = mid;
  }
  const float thr0 = key2f(lo);   // kept set {s >= thr0} == exact top-64 set

  // exact s64 = min over kept set
  float mk = 3.4e38f;
  #pragma unroll
  for (int i = 0; i < 32; ++i) mk = (s[i] >= thr0) ? fminf(mk, s[i]) : mk;
  #pragma unroll
  for (int o = 32; o; o >>= 1) mk = fminf(mk, __shfl_xor(mk, o));
  const float s64 = mk;

  // ambiguity classification (wave-uniform via ballot)
  int n_hi = 0, n_band = 0;
  #pragma unroll
  for (int i = 0; i < 32; ++i) {
    n_hi   += __popcll(__ballot(s[i] > s64 + GBAND));
    n_band += __popcll(__ballot(fabsf(s[i] - s64) <= GBAND));
  }
  const int r = KNEI - n_hi;
  const bool amb = (n_band != r);
  float fb = (float)r / (float)max(n_band, 1);
  fb = fminf(fmaxf(fb, 0.f), 1.f);

  float z = 0.f;
  #pragma unroll
  for (int i = 0; i < 32; ++i) {
    float f;
    if (amb) {
      f = (s[i] > s64 + GBAND) ? 1.f
        : ((fabsf(s[i] - s64) <= GBAND) ? fb : 0.f);
    } else {
      f = (s[i] >= s64) ? 1.f : 0.f;
    }
    float ex = f * __expf(s[i] - mx);
    s[i] = ex; z += ex;
  }
  #pragma unroll
  for (int o = 32; o; o >>= 1) z += __shfl_xor(z, o);
  const float rz = 1.0f / z;

  #pragma unroll
  for (int i = 0; i < 8; ++i) {
    v4f v = { s[i*4+0]*rz, s[i*4+1]*rz, s[i*4+2]*rz, s[i*4+3]*rz };
    __builtin_nontemporal_store(v, (v4f*)(p + (size_t)(lane + 64*i) * 4));
  }
}

// ---------------------------------------------------------------------------
extern "C" void kernel_launch(void* const* d_in, const int* in_sizes, int n_in,
                              void* d_out, int out_size, void* d_ws, size_t ws_size,
                              hipStream_t stream) {
  const float* x  = (const float*)d_in[0];
  const float* Wq = (const float*)d_in[1];
  const float* Wk = (const float*)d_in[2];
  float* out = (float*)d_out;
  float* ws  = (float*)d_ws;   // 2 * 4096*512 * 4B = 16 MB

  proj_kernel<<<dim3(INNER/64, (BATCH*SEQ)/64, 2), 256, 0, stream>>>(x, Wq, Wk, ws);
  score_kernel<<<dim3(SEQ/128, SEQ/128, BATCH*NHEAD), 256, 0, stream>>>(ws, out);
  topk_softmax_hedge<<<dim3((BATCH*NHEAD*SEQ)/4), 256, 0, stream>>>(out);
}